// Round 5
// baseline (294.820 us; speedup 1.0000x reference)
//
#include <hip/hip_runtime.h>
#include <stdint.h>

#define MDIM 8192
#define NDIM 1536
#define KDIM 3072

#define BM 128
#define BN 128
#define BK 64            // two 32-k planes, each in the R2/R4-proven 64B-row swizzled layout

typedef unsigned short u16;
typedef float  f32x4  __attribute__((ext_vector_type(4)));
typedef __bf16 bf16x4 __attribute__((ext_vector_type(4)));
typedef __bf16 bf16x8 __attribute__((ext_vector_type(8)));

__device__ __forceinline__ u16 f2bf(float f) {
    union { float f; unsigned int u; } v; v.f = f;
    unsigned int u = v.u;
    return (u16)((u + 0x7fffu + ((u >> 16) & 1u)) >> 16);  // RNE
}

// ------- prep: Bt[n][k] = bf16(mask[n][k] * w[k][n]) -------
__global__ void make_b_kernel(const float* __restrict__ w, const float* __restrict__ mask,
                              u16* __restrict__ Bt) {
    __shared__ float sw[64][65];
    const int t  = threadIdx.x;
    const int kb = blockIdx.x % (KDIM / 64);
    const int nb = blockIdx.x / (KDIM / 64);
    const int k0 = kb * 64, n0 = nb * 64;
    {
        const int c4 = t & 15;
        const int r  = t >> 4;
#pragma unroll
        for (int rr = 0; rr < 4; ++rr) {
            int row = rr * 16 + r;
            float4 v = *(const float4*)&w[(size_t)(k0 + row) * NDIM + n0 + c4 * 4];
            sw[row][c4 * 4 + 0] = v.x;
            sw[row][c4 * 4 + 1] = v.y;
            sw[row][c4 * 4 + 2] = v.z;
            sw[row][c4 * 4 + 3] = v.w;
        }
    }
    __syncthreads();
    {
        const int n  = t >> 2;
        const int ks = (t & 3) * 16;
#pragma unroll
        for (int j = 0; j < 4; ++j) {
            int k = ks + j * 4;
            float4 mv = *(const float4*)&mask[(size_t)(n0 + n) * KDIM + k0 + k];
            ushort4 o;
            o.x = f2bf(mv.x * sw[k + 0][n]);
            o.y = f2bf(mv.y * sw[k + 1][n]);
            o.z = f2bf(mv.z * sw[k + 2][n]);
            o.w = f2bf(mv.w * sw[k + 3][n]);
            *(ushort4*)&Bt[(size_t)(n0 + n) * KDIM + k0 + k] = o;
        }
    }
}

// ---------------- GEMM: C[m][n] = sum_k x[m][k]*Bt[n][k] + bias[n] ----------------
// A (x, fp32) is staged MANUALLY: global_load_dwordx4 -> in-register cvt to bf16 ->
// ds_write_b64 into the same swizzled bf16 layout the MFMA fragment reads expect
// (chunk c of row r at slot c ^ ((r>>1)&3); store side: c ^ (lane>>4), identical).
// This removes the xb prep pass (150 MB) and shrinks d_ws to 9.4 MB (less re-poison).
// B (Bt, bf16) stays on the global_load_lds w=16 path, layout unchanged (0 conflicts).
__device__ __forceinline__ void gload_lds16(const void* g, void* l) {
    __builtin_amdgcn_global_load_lds(
        (const __attribute__((address_space(1))) unsigned int*)g,
        (__attribute__((address_space(3))) unsigned int*)l, 16, 0, 0);
}

#define PLANE 4096   // u16 elements per k-plane (128 rows * 32)

__global__ void __launch_bounds__(256, 3)
gemm_kernel(const float* __restrict__ X,  // [M][K] fp32
            const u16* __restrict__ B,    // [N][K] bf16
            const float* __restrict__ bias,
            float* __restrict__ C) {      // [M][N] fp32
    __shared__ u16 sA[2 * PLANE];  // 16 KiB
    __shared__ u16 sB[2 * PLANE];  // 16 KiB

    const int tid  = threadIdx.x;
    const int wave = tid >> 6;
    const int lane = tid & 63;

    const int bx = blockIdx.x % (NDIM / BN);
    const int by = blockIdx.x / (NDIM / BN);
    const int m0 = by * BM, n0 = bx * BN;

    // ---- A staging (manual): wave covers rows [wave*32, wave*32+32) ----
    // load (p,j): lane l -> row wave*32 + j*8 + (l>>3), k = k0 + p*32 + (l&7)*4 (float4)
    const int aq   = lane >> 3;          // 0..7 row-within-group
    const int ac   = lane & 7;           // float4 chunk 0..7 (k)
    // LDS store: row r = wave*32 + j*8 + aq; bf16 chunk c=(ac>>1), half h=(ac&1);
    // slot = c ^ ((r>>1)&3) = c ^ (lane>>4)  [since ((j*8+aq)>>1)&3 == aq>>1 == lane>>4]
    const int lds_a = (wave * 32 + aq) * 32 + (((ac >> 1) ^ (lane >> 4)) * 8) + (ac & 1) * 4;

    // ---- B staging (global_load_lds, as R4): lane l -> row l>>2, chunk (l&3)^((l>>3)&3)
    const int bsrow = lane >> 2;
    const int bscol = ((lane & 3) ^ ((lane >> 3) & 3)) * 8;

    const int wm = (wave >> 1) * 64;
    const int wn = (wave & 1) * 64;
    const int fr = lane & 15;
    const int fq = lane >> 4;
    const int fsw = (fq ^ ((fr >> 1) & 3)) * 8;

    f32x4 acc[4][4] = {};

    const float* gA = X + (size_t)(m0 + wave * 32 + aq) * KDIM + ac * 4;
    const u16*   gB0 = B + (size_t)(n0 + wave * 16 + bsrow) * KDIM + bscol;
    u16* lB00 = &sB[0 * PLANE + (wave * 16) * 32];
    u16* lB01 = &sB[0 * PLANE + (wave * 16 + 64) * 32];
    u16* lB10 = &sB[1 * PLANE + (wave * 16) * 32];
    u16* lB11 = &sB[1 * PLANE + (wave * 16 + 64) * 32];

    // register prefetch of the first A tile
    f32x4 ar[8];
#pragma unroll
    for (int p = 0; p < 2; ++p)
#pragma unroll
        for (int j = 0; j < 4; ++j)
            ar[p * 4 + j] = *(const f32x4*)&gA[(size_t)(j * 8) * KDIM + p * 32];

    for (int k0 = 0; k0 < KDIM; k0 += BK) {
        __syncthreads();   // previous iteration's ds_reads complete; LDS reusable
        // stage A from prefetched registers: cvt fp32x4 -> bf16x4, ds_write_b64
#pragma unroll
        for (int p = 0; p < 2; ++p)
#pragma unroll
            for (int j = 0; j < 4; ++j) {
                f32x4 v = ar[p * 4 + j];
                bf16x4 o;
#pragma unroll
                for (int e = 0; e < 4; ++e) o[e] = (__bf16)v[e];
                *(bf16x4*)&sA[p * PLANE + j * 256 + lds_a] = o;
            }
        // B: async direct-to-LDS
        gload_lds16(gB0 + k0,                           lB00);
        gload_lds16(gB0 + k0 + (size_t)64 * KDIM,       lB01);
        gload_lds16(gB0 + k0 + 32,                      lB10);
        gload_lds16(gB0 + k0 + 32 + (size_t)64 * KDIM,  lB11);
        // prefetch next A tile (latency shares the barrier drain with B's gloads)
        if (k0 + BK < KDIM) {
            const float* gAn = gA + k0 + BK;
#pragma unroll
            for (int p = 0; p < 2; ++p)
#pragma unroll
                for (int j = 0; j < 4; ++j)
                    ar[p * 4 + j] = *(const f32x4*)&gAn[(size_t)(j * 8) * KDIM + p * 32];
        }
        __syncthreads();   // drains vmcnt (B gload + A prefetch) + lgkm (A ds_writes)

#pragma unroll
        for (int h = 0; h < 2; ++h) {
            const u16* pA = &sA[h * PLANE];
            const u16* pB = &sB[h * PLANE];
            bf16x8 af[4], bfv[4];
#pragma unroll
            for (int mt = 0; mt < 4; ++mt)
                af[mt] = *(const bf16x8*)&pA[(wm + mt * 16 + fr) * 32 + fsw];
#pragma unroll
            for (int nt = 0; nt < 4; ++nt)
                bfv[nt] = *(const bf16x8*)&pB[(wn + nt * 16 + fr) * 32 + fsw];
#pragma unroll
            for (int mt = 0; mt < 4; ++mt)
#pragma unroll
                for (int nt = 0; nt < 4; ++nt)
                    acc[mt][nt] = __builtin_amdgcn_mfma_f32_16x16x32_bf16(
                        af[mt], bfv[nt], acc[mt][nt], 0, 0, 0);
        }
    }

    // epilogue: C/D layout col = lane&15, row = (lane>>4)*4 + reg  [m89-verified]
#pragma unroll
    for (int nt = 0; nt < 4; ++nt) {
        int n = n0 + wn + nt * 16 + fr;
        float bv = bias[n];
#pragma unroll
        for (int mt = 0; mt < 4; ++mt) {
            int m = m0 + wm + mt * 16 + fq * 4;
#pragma unroll
            for (int r = 0; r < 4; ++r)
                C[(size_t)(m + r) * NDIM + n] = acc[mt][nt][r] + bv;
        }
    }
}

extern "C" void kernel_launch(void* const* d_in, const int* in_sizes, int n_in,
                              void* d_out, int out_size, void* d_ws, size_t ws_size,
                              hipStream_t stream) {
    const float* x    = (const float*)d_in[0];   // [8192][3072]
    const float* w    = (const float*)d_in[1];   // [3072][1536]
    const float* bias = (const float*)d_in[2];   // [1536]
    const float* mask = (const float*)d_in[3];   // [1536][3072]
    float* out = (float*)d_out;                  // [8192][1536]

    u16* Bt = (u16*)d_ws;                        // 1536*3072*2 = 9437184 B (entire ws use)

    make_b_kernel<<<(KDIM / 64) * (NDIM / 64), 256, 0, stream>>>(w, mask, Bt);
    gemm_kernel<<<(MDIM / BM) * (NDIM / BN), 256, 0, stream>>>(x, Bt, bias, out);
}

// Round 6
// 281.543 us; speedup vs baseline: 1.0472x; 1.0472x over previous
//
#include <hip/hip_runtime.h>
#include <stdint.h>

#define MDIM 8192
#define NDIM 1536
#define KDIM 3072

#define BM 128
#define BN 128
#define BK 96            // three 32-k planes, each in the R2/R4-proven 64B-row swizzled layout

#define NMB ((KDIM / 64) * (NDIM / 64))
#define NCVT ((MDIM * KDIM / 4) / 256)

typedef unsigned short u16;
typedef float  f32x4  __attribute__((ext_vector_type(4)));
typedef __bf16 bf16x8 __attribute__((ext_vector_type(8)));

__device__ __forceinline__ u16 f2bf(float f) {
    union { float f; unsigned int u; } v; v.f = f;
    unsigned int u = v.u;
    return (u16)((u + 0x7fffu + ((u >> 16) & 1u)) >> 16);  // RNE
}

// ---------------- fused prep: make_b blocks, then cvt_x blocks ----------------
__global__ void prep_kernel(const float* __restrict__ w, const float* __restrict__ mask,
                            u16* __restrict__ Bt,
                            const float4* __restrict__ x, ushort4* __restrict__ xb) {
    const int t = threadIdx.x;
    if (blockIdx.x < NMB) {
        __shared__ float sw[64][65];
        const int kb = blockIdx.x % (KDIM / 64);
        const int nb = blockIdx.x / (KDIM / 64);
        const int k0 = kb * 64, n0 = nb * 64;
        {
            const int c4 = t & 15;
            const int r  = t >> 4;
#pragma unroll
            for (int rr = 0; rr < 4; ++rr) {
                int row = rr * 16 + r;
                float4 v = *(const float4*)&w[(size_t)(k0 + row) * NDIM + n0 + c4 * 4];
                sw[row][c4 * 4 + 0] = v.x;
                sw[row][c4 * 4 + 1] = v.y;
                sw[row][c4 * 4 + 2] = v.z;
                sw[row][c4 * 4 + 3] = v.w;
            }
        }
        __syncthreads();
        {
            const int n  = t >> 2;
            const int ks = (t & 3) * 16;
#pragma unroll
            for (int j = 0; j < 4; ++j) {
                int k = ks + j * 4;
                float4 mv = *(const float4*)&mask[(size_t)(n0 + n) * KDIM + k0 + k];
                ushort4 o;
                o.x = f2bf(mv.x * sw[k + 0][n]);
                o.y = f2bf(mv.y * sw[k + 1][n]);
                o.z = f2bf(mv.z * sw[k + 2][n]);
                o.w = f2bf(mv.w * sw[k + 3][n]);
                *(ushort4*)&Bt[(size_t)(n0 + n) * KDIM + k0 + k] = o;
            }
        }
    } else {
        int i = (blockIdx.x - NMB) * 256 + t;
        float4 v = x[i];
        ushort4 o;
        o.x = f2bf(v.x); o.y = f2bf(v.y); o.z = f2bf(v.z); o.w = f2bf(v.w);
        xb[i] = o;
    }
}

// ---------------- GEMM: C[m][n] = sum_k A[m][k]*Bt[n][k] + bias[n] ----------------
// R4 structure + (a) XCD-aware block swizzle: blocks with blockIdx%8==r (dispatched to
// XCD r round-robin) share a contiguous 8-wide by-band, so A/B tile re-reads hit that
// XCD's L2 (latency-bound loop -> shorter barrier drain); (b) BK=96 = three 32-k planes
// (barriers 96 -> 64), each plane byte-identical to the measured-0-conflict layout:
// 16B chunk (row r, c) at slot 4r + (c ^ ((r>>1)&3)), swizzle applied on global source.
__device__ __forceinline__ void gload_lds16(const void* g, void* l) {
    __builtin_amdgcn_global_load_lds(
        (const __attribute__((address_space(1))) unsigned int*)g,
        (__attribute__((address_space(3))) unsigned int*)l, 16, 0, 0);
}

#define PLANE 4096   // u16 per k-plane (128 rows * 32)

__global__ void __launch_bounds__(256, 3)
gemm_kernel(const u16* __restrict__ A,   // [M][K] bf16
            const u16* __restrict__ B,   // [N][K] bf16
            const float* __restrict__ bias,
            float* __restrict__ C) {     // [M][N] fp32
    __shared__ u16 sA[3 * PLANE];  // 24 KiB
    __shared__ u16 sB[3 * PLANE];  // 24 KiB

    const int tid  = threadIdx.x;
    const int wave = tid >> 6;
    const int lane = tid & 63;

    // XCD-affine remap: bik = bx*64 + l*8 + xcd  ->  by = xcd*8 + l, bx = bik>>6
    const int bik = blockIdx.x;
    const int by  = (bik & 7) * 8 + ((bik >> 3) & 7);
    const int bx  = bik >> 6;
    const int m0 = by * BM, n0 = bx * BN;

    const int srow = lane >> 2;
    const int scol = ((lane & 3) ^ ((lane >> 3) & 3)) * 8;

    const int wm = (wave >> 1) * 64;
    const int wn = (wave & 1) * 64;
    const int fr = lane & 15;
    const int fq = lane >> 4;
    const int fsw = (fq ^ ((fr >> 1) & 3)) * 8;

    f32x4 acc[4][4] = {};

    const u16* gA0 = A + (size_t)(m0 + wave * 16 + srow) * KDIM + scol;
    const u16* gB0 = B + (size_t)(n0 + wave * 16 + srow) * KDIM + scol;
    u16* lA0 = &sA[(wave * 16) * 32];
    u16* lA1 = &sA[(wave * 16 + 64) * 32];
    u16* lB0 = &sB[(wave * 16) * 32];
    u16* lB1 = &sB[(wave * 16 + 64) * 32];

    for (int k0 = 0; k0 < KDIM; k0 += BK) {
        __syncthreads();
#pragma unroll
        for (int p = 0; p < 3; ++p) {
            gload_lds16(gA0 + k0 + p * 32,                      lA0 + p * PLANE);
            gload_lds16(gA0 + k0 + p * 32 + (size_t)64 * KDIM,  lA1 + p * PLANE);
            gload_lds16(gB0 + k0 + p * 32,                      lB0 + p * PLANE);
            gload_lds16(gB0 + k0 + p * 32 + (size_t)64 * KDIM,  lB1 + p * PLANE);
        }
        __syncthreads();

#pragma unroll
        for (int h = 0; h < 3; ++h) {
            const u16* pA = &sA[h * PLANE];
            const u16* pB = &sB[h * PLANE];
            bf16x8 af[4], bfv[4];
#pragma unroll
            for (int mt = 0; mt < 4; ++mt)
                af[mt] = *(const bf16x8*)&pA[(wm + mt * 16 + fr) * 32 + fsw];
#pragma unroll
            for (int nt = 0; nt < 4; ++nt)
                bfv[nt] = *(const bf16x8*)&pB[(wn + nt * 16 + fr) * 32 + fsw];
#pragma unroll
            for (int mt = 0; mt < 4; ++mt)
#pragma unroll
                for (int nt = 0; nt < 4; ++nt)
                    acc[mt][nt] = __builtin_amdgcn_mfma_f32_16x16x32_bf16(
                        af[mt], bfv[nt], acc[mt][nt], 0, 0, 0);
        }
    }

    // epilogue: C/D layout col = lane&15, row = (lane>>4)*4 + reg  [m89-verified]
#pragma unroll
    for (int nt = 0; nt < 4; ++nt) {
        int n = n0 + wn + nt * 16 + fr;
        float bv = bias[n];
#pragma unroll
        for (int mt = 0; mt < 4; ++mt) {
            int m = m0 + wm + mt * 16 + fq * 4;
#pragma unroll
            for (int r = 0; r < 4; ++r)
                C[(size_t)(m + r) * NDIM + n] = acc[mt][nt][r] + bv;
        }
    }
}

extern "C" void kernel_launch(void* const* d_in, const int* in_sizes, int n_in,
                              void* d_out, int out_size, void* d_ws, size_t ws_size,
                              hipStream_t stream) {
    const float* x    = (const float*)d_in[0];   // [8192][3072]
    const float* w    = (const float*)d_in[1];   // [3072][1536]
    const float* bias = (const float*)d_in[2];   // [1536]
    const float* mask = (const float*)d_in[3];   // [1536][3072]
    float* out = (float*)d_out;                  // [8192][1536]

    u16* xb = (u16*)d_ws;                                   // 50331648 B
    u16* Bt = (u16*)((char*)d_ws + (size_t)50331648);       //  9437184 B

    prep_kernel<<<NMB + NCVT, 256, 0, stream>>>(w, mask, Bt, (const float4*)x, (ushort4*)xb);
    gemm_kernel<<<(MDIM / BM) * (NDIM / BN), 256, 0, stream>>>(xb, Bt, bias, out);
}